// Round 11
// baseline (273.999 us; speedup 1.0000x reference)
//
#include <hip/hip_runtime.h>

#define F_IN 128
#define RDIM 128
#define KTOT 384   // 2*F_IN + RDIM
#define ALPHA 0.2f

typedef short bf8 __attribute__((ext_vector_type(8)));   // 8 bf16 = 4 VGPRs
typedef float f4 __attribute__((ext_vector_type(4)));
typedef float fv4 __attribute__((ext_vector_type(4)));   // plain-vec float4 (nt-capable)
typedef int   iv4 __attribute__((ext_vector_type(4)));   // plain-vec int4   (nt-capable)
typedef int   iv2 __attribute__((ext_vector_type(2)));   // plain-vec int2   (nt-capable)

__device__ inline unsigned short f2bf(float f) {
  unsigned u = __float_as_uint(f);
  unsigned r = u + 0x7FFFu + ((u >> 16) & 1u);   // round-nearest-even
  return (unsigned short)(r >> 16);
}
__device__ inline float bf2f(unsigned short b) {
  return __uint_as_float((unsigned)b << 16);
}

// ---------- K_prep: fused {a -> bf16 | zero counts | w = a^T a_2} ----------
__global__ __launch_bounds__(256) void k_prep(const float* __restrict__ a,
                                              const float* __restrict__ a2,
                                              unsigned short* __restrict__ aB,
                                              int* __restrict__ counts,
                                              float* __restrict__ w,
                                              int N, int zb) {
  int b = blockIdx.x, t = threadIdx.x;
  if (b < 192) {
    int i = b * 256 + t;                     // < 49152 always
    aB[i] = f2bf(a[i]);
  } else if (b < 192 + zb) {
    int i = (b - 192) * 256 + t;
    if (i < N) counts[i] = 0;
  } else {
    int j = (b - 192 - zb) * 256 + t;
    if (j < KTOT) {
      float acc = 0.f;
      for (int f = 0; f < 128; ++f) acc += a2[f] * a[(size_t)f * KTOT + j];
      w[j] = acc;
    }
  }
}

// ---------- K_sh: fused { svec (s1,s2,inputB) | hist (counts atomics) } ----------
__global__ __launch_bounds__(256) void k_sh(const float* __restrict__ input,
                                            const float* __restrict__ w1,
                                            const float* __restrict__ w2,
                                            float* __restrict__ s1,
                                            float* __restrict__ s2,
                                            unsigned short* __restrict__ inputB,
                                            const int* __restrict__ edge_src,
                                            int* __restrict__ counts,
                                            int N, int E, int SV) {
  int b = blockIdx.x, t = threadIdx.x;
  if (b < SV) {
    int lane = t & 63;
    int n = b * 4 + (t >> 6);
    if (n >= N) return;
    float2 x  = *(const float2*)(input + (size_t)n * F_IN + 2 * lane);
    float2 wa = *(const float2*)(w1 + 2 * lane);
    float2 wb = *(const float2*)(w2 + 2 * lane);
    ushort2 ib; ib.x = f2bf(x.x); ib.y = f2bf(x.y);
    *(ushort2*)(inputB + (size_t)n * F_IN + 2 * lane) = ib;
    float p1 = x.x * wa.x + x.y * wa.y;
    float p2 = x.x * wb.x + x.y * wb.y;
    #pragma unroll
    for (int m = 1; m < 64; m <<= 1) {
      p1 += __shfl_xor(p1, m, 64);
      p2 += __shfl_xor(p2, m, 64);
    }
    if (lane == 0) { s1[n] = p1; s2[n] = p2; }
  } else {
    int i = (b - SV) * 1024 + 4 * t;
    if (i + 3 < E) {
      iv4 s = *(const iv4*)(edge_src + i);
      atomicAdd(&counts[s.x], 1);
      atomicAdd(&counts[s.y], 1);
      atomicAdd(&counts[s.z], 1);
      atomicAdd(&counts[s.w], 1);
    } else {
      for (int j = i; j < E; ++j) atomicAdd(&counts[edge_src[j]], 1);
    }
  }
}

// ---------- multi-block exclusive scan: A = local scan + block sums ----------
__global__ __launch_bounds__(256) void k_scanA(const int* __restrict__ counts,
                                               int* __restrict__ row_ptr,
                                               int* __restrict__ bsums, int N) {
  __shared__ int sh[256];
  int b = blockIdx.x, t = threadIdx.x;
  int i0 = b * 1024 + 4 * t;
  iv4 c; c.x = 0; c.y = 0; c.z = 0; c.w = 0;
  if (i0 + 3 < N) c = *(const iv4*)(counts + i0);
  else {
    if (i0 + 0 < N) c.x = counts[i0 + 0];
    if (i0 + 1 < N) c.y = counts[i0 + 1];
    if (i0 + 2 < N) c.z = counts[i0 + 2];
    if (i0 + 3 < N) c.w = counts[i0 + 3];
  }
  int s = c.x + c.y + c.z + c.w;
  sh[t] = s;
  __syncthreads();
  #pragma unroll
  for (int off = 1; off < 256; off <<= 1) {
    int v = (t >= off) ? sh[t - off] : 0;
    __syncthreads();
    sh[t] += v;
    __syncthreads();
  }
  int excl = sh[t] - s;
  iv4 o;
  o.x = excl;
  o.y = excl + c.x;
  o.z = excl + c.x + c.y;
  o.w = excl + c.x + c.y + c.z;
  if (i0 + 3 < N) *(iv4*)(row_ptr + i0) = o;
  else {
    if (i0 + 0 < N) row_ptr[i0 + 0] = o.x;
    if (i0 + 1 < N) row_ptr[i0 + 1] = o.y;
    if (i0 + 2 < N) row_ptr[i0 + 2] = o.z;
    if (i0 + 3 < N) row_ptr[i0 + 3] = o.w;
  }
  if (t == 255) bsums[b] = sh[255];
}

// ---------- scan B: add block offsets (in place) + cursor init + row_ptr[N] ----
__global__ __launch_bounds__(256) void k_scanB(int* __restrict__ row_ptr,
                                               int* __restrict__ cursor,
                                               const int* __restrict__ bsums,
                                               int N, int NB) {
  int b = blockIdx.x, t = threadIdx.x, lane = t & 63;
  int off = 0, total = 0;
  for (int j = lane; j < NB; j += 64) {
    int v = bsums[j];
    if (j < b) off += v;
    total += v;
  }
  #pragma unroll
  for (int m = 1; m < 64; m <<= 1) {
    off += __shfl_xor(off, m, 64);
    total += __shfl_xor(total, m, 64);
  }
  int i0 = b * 1024 + 4 * t;
  if (i0 + 3 < N) {
    iv4 v = *(const iv4*)(row_ptr + i0);
    v.x += off; v.y += off; v.z += off; v.w += off;
    *(iv4*)(row_ptr + i0) = v;
    *(iv4*)(cursor + i0) = v;
  } else {
    for (int j = i0; j < N && j < i0 + 4; ++j) {
      int v = row_ptr[j] + off;
      row_ptr[j] = v;
      cursor[j] = v;
    }
  }
  if (b == NB - 1 && t == 0) row_ptr[N] = total;
}

// ---------- K_scatter: pack {e, dst} (8B) into CSR slots ----------
__global__ __launch_bounds__(256) void k_scatter(const int* __restrict__ edge_src,
                                                 const int* __restrict__ edge_dst,
                                                 int* __restrict__ cursor,
                                                 iv2* __restrict__ csr_pack, int E) {
  int e = blockIdx.x * 256 + threadIdx.x;
  if (e >= E) return;
  int src = edge_src[e];
  int dst = edge_dst[e];
  int pos = atomicAdd(&cursor[src], 1);
  iv2 pk; pk.x = e; pk.y = dst;
  __builtin_nontemporal_store(pk, &csr_pack[pos]);
}

// ---------- K_edge: per-node wave; 2 edges/iter; depth-3 ring (6 in flight);
//            bf16 input gather; s2 gathered from L2; nt emb/csr; bf16 G ----------
__global__ __launch_bounds__(256) void k_edge(const unsigned short* __restrict__ inputB,
                                              const float* __restrict__ emb,
                                              const float* __restrict__ w3,
                                              const float* __restrict__ s1,
                                              const float* __restrict__ s2,
                                              const int* __restrict__ row_ptr,
                                              const iv2* __restrict__ csr_pack,
                                              unsigned short* __restrict__ Gb,
                                              float* __restrict__ rs, int N) {
  int lane = threadIdx.x & 63;
  int h = lane >> 5;     // which edge of the pair
  int c = lane & 31;     // feature sublane: features 4c..4c+3
  int n = blockIdx.x * 4 + (threadIdx.x >> 6);
  if (n >= N) return;
  int beg = row_ptr[n], end = row_ptr[n + 1];
  fv4 w3v = *(const fv4*)(w3 + 4 * c);
  float s1n = s1[n];
  fv4 gi = (fv4)(0.f), ge = (fv4)(0.f);
  float rsum = 0.f;

  fv4 z4 = (fv4)(0.f);
  ushort4 zy = make_ushort4(0, 0, 0, 0);
  fv4 x0 = z4, x1 = z4, x2 = z4;
  ushort4 y0 = zy, y1 = zy, y2 = zy;
  float sv0 = 0.f, sv1 = 0.f, sv2 = 0.f;
  bool va0 = false, va1 = false, va2 = false;
  iv2 pN; pN.x = 0; pN.y = 0;

  int i0 = beg + h;
  if (i0 < end) {
    iv2 p = __builtin_nontemporal_load(&csr_pack[i0]);
    x0 = __builtin_nontemporal_load((const fv4*)(emb + (size_t)p.x * RDIM + 4 * c));
    y0 = *(const ushort4*)(inputB + (size_t)p.y * F_IN + 4 * c);
    sv0 = s2[p.y];
    va0 = true;
  }
  if (i0 + 2 < end) {
    iv2 p = __builtin_nontemporal_load(&csr_pack[i0 + 2]);
    x1 = __builtin_nontemporal_load((const fv4*)(emb + (size_t)p.x * RDIM + 4 * c));
    y1 = *(const ushort4*)(inputB + (size_t)p.y * F_IN + 4 * c);
    sv1 = s2[p.y];
    va1 = true;
  }
  if (i0 + 4 < end) {
    iv2 p = __builtin_nontemporal_load(&csr_pack[i0 + 4]);
    x2 = __builtin_nontemporal_load((const fv4*)(emb + (size_t)p.x * RDIM + 4 * c));
    y2 = *(const ushort4*)(inputB + (size_t)p.y * F_IN + 4 * c);
    sv2 = s2[p.y];
    va2 = true;
  }
  if (i0 + 6 < end) pN = __builtin_nontemporal_load(&csr_pack[i0 + 6]);

  for (int i = beg; i < end; i += 2) {
    // refill slot3 data (edge i+6+h) from payload loaded last iteration
    fv4 xn = z4;
    ushort4 yn = zy;
    float svn = 0.f;
    bool vn = (i + 6 + h) < end;
    if (vn) {
      xn = __builtin_nontemporal_load((const fv4*)(emb + (size_t)pN.x * RDIM + 4 * c));
      yn = *(const ushort4*)(inputB + (size_t)pN.y * F_IN + 4 * c);
      svn = s2[pN.y];
    }
    // payload for edge i+8+h
    if (i + 8 + h < end) pN = __builtin_nontemporal_load(&csr_pack[i + 8 + h]);
    // compute on slot 0
    float q = x0.x * w3v.x + x0.y * w3v.y + x0.z * w3v.z + x0.w * w3v.w;
    #pragma unroll
    for (int m = 1; m < 32; m <<= 1) q += __shfl_xor(q, m, 64);  // within-half reduce
    float s = s1n + sv0 + q;
    float lr = s > 0.f ? s : ALPHA * s;
    float ee = va0 ? __expf(-lr) : 0.f;
    rsum += ee;
    gi.x += ee * bf2f(y0.x); gi.y += ee * bf2f(y0.y);
    gi.z += ee * bf2f(y0.z); gi.w += ee * bf2f(y0.w);
    ge.x += ee * x0.x; ge.y += ee * x0.y; ge.z += ee * x0.z; ge.w += ee * x0.w;
    // rotate ring (static renaming — stays in registers)
    x0 = x1; y0 = y1; sv0 = sv1; va0 = va1;
    x1 = x2; y1 = y2; sv1 = sv2; va1 = va2;
    x2 = xn; y2 = yn; sv2 = svn; va2 = vn;
  }

  rsum += __shfl_xor(rsum, 32, 64);
  gi.x += __shfl_xor(gi.x, 32, 64); gi.y += __shfl_xor(gi.y, 32, 64);
  gi.z += __shfl_xor(gi.z, 32, 64); gi.w += __shfl_xor(gi.w, 32, 64);
  ge.x += __shfl_xor(ge.x, 32, 64); ge.y += __shfl_xor(ge.y, 32, 64);
  ge.z += __shfl_xor(ge.z, 32, 64); ge.w += __shfl_xor(ge.w, 32, 64);

  float scale = rsum > 0.f ? 1.f / rsum : 0.f;
  if (h == 0) {
    unsigned short* Gn = Gb + (size_t)n * 256;
    ushort4 o;
    o.x = f2bf(gi.x * scale); o.y = f2bf(gi.y * scale);
    o.z = f2bf(gi.z * scale); o.w = f2bf(gi.w * scale);
    *(ushort4*)(Gn + 4 * c) = o;
    o.x = f2bf(ge.x * scale); o.y = f2bf(ge.y * scale);
    o.z = f2bf(ge.z * scale); o.w = f2bf(ge.w * scale);
    *(ushort4*)(Gn + 128 + 4 * c) = o;
  }
  if (lane == 0) rs[n] = rsum;
}

// ---------- K_out: MFMA bf16 GEMM: out = elu([inputB | Gb] @ aB^T), rs==0 -> 0 ----
__global__ __launch_bounds__(256) void k_out(const unsigned short* __restrict__ inputB,
                                             const unsigned short* __restrict__ Gb,
                                             const unsigned short* __restrict__ aB,
                                             const float* __restrict__ rs,
                                             float* __restrict__ out, int N) {
  int t = threadIdx.x;
  int w = t >> 6, lane = t & 63;
  int lg = lane >> 4, lr = lane & 15;
  int rowbase = blockIdx.x * 128 + w * 32;
  int koff = lg * 8;

  f4 acc[2][8];
  #pragma unroll
  for (int r = 0; r < 2; ++r)
    #pragma unroll
    for (int c = 0; c < 8; ++c) acc[r][c] = (f4)(0.f);

  #pragma unroll
  for (int ks = 0; ks < 12; ++ks) {
    const int k0 = ks * 32;
    bf8 Af[2], Bf[8];
    #pragma unroll
    for (int r = 0; r < 2; ++r) {
      int row = rowbase + r * 16 + lr;
      if (k0 < 128)
        Af[r] = *(const bf8*)(inputB + (size_t)row * 128 + k0 + koff);
      else
        Af[r] = *(const bf8*)(Gb + (size_t)row * 256 + (k0 - 128) + koff);
    }
    #pragma unroll
    for (int c = 0; c < 8; ++c)
      Bf[c] = *(const bf8*)(aB + (size_t)(c * 16 + lr) * KTOT + k0 + koff);
    #pragma unroll
    for (int r = 0; r < 2; ++r)
      #pragma unroll
      for (int c = 0; c < 8; ++c)
        acc[r][c] = __builtin_amdgcn_mfma_f32_16x16x32_bf16(Af[r], Bf[c], acc[r][c], 0, 0, 0);
  }

  #pragma unroll
  for (int r = 0; r < 2; ++r) {
    #pragma unroll
    for (int j = 0; j < 4; ++j) {
      int row = rowbase + r * 16 + lg * 4 + j;
      if (row >= N) continue;
      float rsv = rs[row];
      #pragma unroll
      for (int c = 0; c < 8; ++c) {
        float v = acc[r][c][j];
        float hh = v > 0.f ? v : (__expf(v) - 1.f);
        out[(size_t)row * 128 + c * 16 + lr] = (rsv == 0.f) ? 0.f : hh;
      }
    }
  }
}

extern "C" void kernel_launch(void* const* d_in, const int* in_sizes, int n_in,
                              void* d_out, int out_size, void* d_ws, size_t ws_size,
                              hipStream_t stream) {
  const float* input      = (const float*)d_in[0];
  const int*   edge       = (const int*)d_in[1];   // int32 [2,E] row-major
  const float* edge_embed = (const float*)d_in[2];
  const float* a          = (const float*)d_in[3];
  const float* a_2        = (const float*)d_in[4];
  float* out = (float*)d_out;
  int N = in_sizes[0] / F_IN;
  int E = in_sizes[1] / 2;
  const int* edge_src = edge;
  const int* edge_dst = edge + E;

  char* p = (char*)d_ws;
  auto take = [&](size_t bytes) { char* q = p; p += (bytes + 255) & ~(size_t)255; return q; };
  float* w        = (float*)take(KTOT * 4);        // w1|w2|w3 contiguous
  float* s1       = (float*)take((size_t)N * 4);
  float* s2       = (float*)take((size_t)N * 4);
  float* rs       = (float*)take((size_t)N * 4);
  int*   counts   = (int*)take((size_t)N * 4);
  int*   cursor   = (int*)take((size_t)N * 4);
  int*   row_ptr  = (int*)take((size_t)(N + 1) * 4);
  int*   bsums    = (int*)take(256 * 4);
  unsigned short* aB     = (unsigned short*)take((size_t)128 * KTOT * 2);
  unsigned short* inputB = (unsigned short*)take((size_t)N * 128 * 2);
  iv2*  csr_pack  = (iv2*)take((size_t)E * 8);
  unsigned short* Gb     = (unsigned short*)take((size_t)N * 256 * 2);
  (void)take(64 * 1024);   // tail pad: k_out overreads <=48 rows past N

  int zb = (N + 255) / 256;
  int SV = (N + 3) / 4;
  int HB = (E + 1023) / 1024;
  int NB = (N + 1023) / 1024;

  k_prep<<<192 + zb + 2, 256, 0, stream>>>(a, a_2, aB, counts, w, N, zb);
  k_sh<<<SV + HB, 256, 0, stream>>>(input, w, w + 128, s1, s2, inputB,
                                    edge_src, counts, N, E, SV);
  k_scanA<<<NB, 256, 0, stream>>>(counts, row_ptr, bsums, N);
  k_scanB<<<NB, 256, 0, stream>>>(row_ptr, cursor, bsums, N, NB);
  k_scatter<<<(E + 255) / 256, 256, 0, stream>>>(edge_src, edge_dst, cursor,
                                                 csr_pack, E);
  k_edge<<<(N + 3) / 4, 256, 0, stream>>>(inputB, edge_embed, w + 256, s1, s2,
                                          row_ptr, csr_pack, Gb, rs, N);
  k_out<<<(N + 127) / 128, 256, 0, stream>>>(inputB, Gb, aB, rs, out, N);
}